// Round 7
// baseline (2886.555 us; speedup 1.0000x reference)
//
#include <hip/hip_runtime.h>
#include <math.h>

// TransformersLSTM: T=512, I=512, H=1024, L=512, O=1.
// Split-grid persistent kernel: blocks 0..127 encoder, 128..255 decoder.
// Weights VGPR-resident. Tagless handoff on 0xAA-poisoned write-once buffers.
// R7: (1) pipelined 2-deep poison-polling in one asm block (sampling ~RTT/2);
// (2) wave-autonomous cells: each wave owns 2 h-lanes x 4 gates, gate exchange
// via in-wave shuffles -> encoder 1 barrier/step, decoder 2; (3) replication
// removed (R6 falsified line-contention); (4) parity-double-buffered LDS.

#define T_STEPS 512
#define ENC_BLK 128
#define NBLK    256

typedef float fv4 __attribute__((ext_vector_type(4)));

__device__ __forceinline__ float sigf(float x) { return 1.0f / (1.0f + expf(-x)); }

// 4B cache-bypass store (write-through to LLC).
__device__ __forceinline__ void st_bypass4(float* p, float v) {
  asm volatile("global_store_dword %0, %1, off sc0 sc1"
               :: "v"(p), "v"(v) : "memory");
}

// Pipelined poison-poll of one 16B granule: two 4-dword sample groups in
// flight, sliding vmcnt window. Wave exits when ALL lanes' granules are
// poison-free. Self-contained (all waitcnts internal; exits drained).
__device__ __forceinline__ fv4 poll_pipe(const float* p, int* okp) {
  float a0, a1, a2, a3, b0, b1, b2, b3;
  unsigned flag, cnt;
  asm volatile(
      "s_mov_b32 %8, 0\n\t"
      "s_mov_b32 %9, 0\n\t"
      "global_load_dword %0, %10, off sc0 sc1\n\t"
      "global_load_dword %1, %10, off offset:4 sc0 sc1\n\t"
      "global_load_dword %2, %10, off offset:8 sc0 sc1\n\t"
      "global_load_dword %3, %10, off offset:12 sc0 sc1\n\t"
      "PLA%=:\n\t"
      "global_load_dword %4, %10, off sc0 sc1\n\t"
      "global_load_dword %5, %10, off offset:4 sc0 sc1\n\t"
      "global_load_dword %6, %10, off offset:8 sc0 sc1\n\t"
      "global_load_dword %7, %10, off offset:12 sc0 sc1\n\t"
      "s_waitcnt vmcnt(4)\n\t"
      "v_cmp_eq_u32 vcc, 0xaaaaaaaa, %0\n\t"
      "s_cbranch_vccnz PRB%=\n\t"
      "v_cmp_eq_u32 vcc, 0xaaaaaaaa, %1\n\t"
      "s_cbranch_vccnz PRB%=\n\t"
      "v_cmp_eq_u32 vcc, 0xaaaaaaaa, %2\n\t"
      "s_cbranch_vccnz PRB%=\n\t"
      "v_cmp_eq_u32 vcc, 0xaaaaaaaa, %3\n\t"
      "s_cbranch_vccnz PRB%=\n\t"
      "s_waitcnt vmcnt(0)\n\t"
      "s_branch PDONE%=\n\t"
      "PRB%=:\n\t"
      "s_add_u32 %9, %9, 1\n\t"
      "s_cmp_lt_u32 %9, 0xc350\n\t"
      "s_cbranch_scc0 PTO%=\n\t"
      "global_load_dword %0, %10, off sc0 sc1\n\t"
      "global_load_dword %1, %10, off offset:4 sc0 sc1\n\t"
      "global_load_dword %2, %10, off offset:8 sc0 sc1\n\t"
      "global_load_dword %3, %10, off offset:12 sc0 sc1\n\t"
      "s_waitcnt vmcnt(4)\n\t"
      "v_cmp_eq_u32 vcc, 0xaaaaaaaa, %4\n\t"
      "s_cbranch_vccnz PRA%=\n\t"
      "v_cmp_eq_u32 vcc, 0xaaaaaaaa, %5\n\t"
      "s_cbranch_vccnz PRA%=\n\t"
      "v_cmp_eq_u32 vcc, 0xaaaaaaaa, %6\n\t"
      "s_cbranch_vccnz PRA%=\n\t"
      "v_cmp_eq_u32 vcc, 0xaaaaaaaa, %7\n\t"
      "s_cbranch_vccnz PRA%=\n\t"
      "s_waitcnt vmcnt(0)\n\t"
      "v_mov_b32 %0, %4\n\t"
      "v_mov_b32 %1, %5\n\t"
      "v_mov_b32 %2, %6\n\t"
      "v_mov_b32 %3, %7\n\t"
      "s_branch PDONE%=\n\t"
      "PRA%=:\n\t"
      "s_add_u32 %9, %9, 1\n\t"
      "s_cmp_lt_u32 %9, 0xc350\n\t"
      "s_cbranch_scc0 PTO%=\n\t"
      "s_branch PLA%=\n\t"
      "PTO%=:\n\t"
      "s_mov_b32 %8, 1\n\t"
      "s_waitcnt vmcnt(0)\n\t"
      "PDONE%=:"
      : "=&v"(a0), "=&v"(a1), "=&v"(a2), "=&v"(a3),
        "=&v"(b0), "=&v"(b1), "=&v"(b2), "=&v"(b3),
        "=&s"(flag), "=&s"(cnt)
      : "v"(p)
      : "vcc", "scc", "memory");
  *okp = (flag == 0);
  fv4 r;
  r.x = a0; r.y = a1; r.z = a2; r.w = a3;
  return r;
}

// ------------- precompute PX = W_ih_e @ x_t + b_ih_e + b_hh_e -----------------
// px[(t*1024 + h)*4 + g] for gate row r = g*1024 + h.
__global__ __launch_bounds__(256) void prep_gemm(const float* __restrict__ X,
                                                 const float* __restrict__ Wih,
                                                 const float* __restrict__ bih,
                                                 const float* __restrict__ bhh,
                                                 float* __restrict__ px) {
  __shared__ float Ws[64][68];
  __shared__ float Xs[64][68];
  const int r0 = blockIdx.x * 64;
  const int t0 = blockIdx.y * 64;
  const int tid = threadIdx.x;
  const int tr = tid & 15;
  const int tc = tid >> 4;
  float acc[4][4] = {{0.f}};
  for (int k0 = 0; k0 < 512; k0 += 64) {
    __syncthreads();
    const int lr = tid >> 4;
    const int lc = (tid & 15) * 4;
#pragma unroll
    for (int rep = 0; rep < 4; rep++) {
      const int row = lr + rep * 16;
      const float4 wv = *(const float4*)&Wih[(size_t)(r0 + row) * 512 + k0 + lc];
      Ws[lc + 0][row] = wv.x; Ws[lc + 1][row] = wv.y;
      Ws[lc + 2][row] = wv.z; Ws[lc + 3][row] = wv.w;
      const float4 xv = *(const float4*)&X[(size_t)(t0 + row) * 512 + k0 + lc];
      Xs[row][lc + 0] = xv.x; Xs[row][lc + 1] = xv.y;
      Xs[row][lc + 2] = xv.z; Xs[row][lc + 3] = xv.w;
    }
    __syncthreads();
    for (int kk = 0; kk < 64; kk++) {
      float a[4], x[4];
#pragma unroll
      for (int i = 0; i < 4; i++) a[i] = Ws[kk][tr * 4 + i];
#pragma unroll
      for (int j = 0; j < 4; j++) x[j] = Xs[tc * 4 + j][kk];
#pragma unroll
      for (int i = 0; i < 4; i++)
#pragma unroll
        for (int j = 0; j < 4; j++) acc[i][j] += a[i] * x[j];
    }
  }
#pragma unroll
  for (int i = 0; i < 4; i++) {
    const int r = r0 + tr * 4 + i;
    const int g = r >> 10, h = r & 1023;
    const float bsum = bih[r] + bhh[r];
#pragma unroll
    for (int j = 0; j < 4; j++) {
      const int t = t0 + tc * 4 + j;
      px[((size_t)t * 1024 + h) * 4 + g] = acc[i][j] + bsum;
    }
  }
}

// ------------------------------ persistent kernel -----------------------------
__global__ __launch_bounds__(256, 1) void lstm_persist(
    const float* __restrict__ Whhe, const float* __restrict__ Wattn,
    const float* __restrict__ battn, const float* __restrict__ Wihd,
    const float* __restrict__ Whhd, const float* __restrict__ bihd,
    const float* __restrict__ bhhd, const float* __restrict__ Wout,
    const float* __restrict__ bout, const float* __restrict__ px,
    float* ehbuf, float* dhbuf, float* out) {
  __shared__ float4 xbufE[2][256];  // encoder eh copy, parity dbuf
  __shared__ float4 xbufD[256];     // decoder eh copy
  __shared__ float4 dbufD[256];     // decoder dh copy
  __shared__ float  aw[512];        // replicated softmax state (decoder)
  __shared__ float  redE[2][4];     // energy (eh part), parity
  __shared__ float  redE2[2][4];    // energy (dh part), parity
  __shared__ float  red[2][4];      // softmax sum, parity
  __shared__ float  red2[4];        // out-dot reduce
  __shared__ int    sbad;

  const int b     = blockIdx.x;
  const int tid   = threadIdx.x;
  const int w     = tid >> 6;    // wave
  const int lane  = tid & 63;
  const int idx   = lane & 7;    // row slot: gate g = idx>>1, h-sub j = idx&1
  const int g     = idx >> 1;
  const int jc    = lane & 1;    // cell gather selector
  const int seg   = lane >> 3;   // K-segment 0..7 (128 floats each)

  if (b < ENC_BLK) {
    // =========================== encoder group ===============================
    const int e = b;
    const int r = (g << 10) + (e << 3) + 2 * w + (idx & 1);  // owned gate row
    float4 we[32];
#pragma unroll
    for (int k = 0; k < 32; k++) {
      const int m = (k + seg) & 31;
      we[k] = *(const float4*)&Whhe[(size_t)r * 1024 + seg * 128 + m * 4];
    }
    xbufE[0][tid] = make_float4(0.f, 0.f, 0.f, 0.f);
    if (tid == 0) sbad = 0;
    float ec = 0.f;  // cell state (lanes 0,1 of each wave)
    __syncthreads();

    for (int t = 0; t < T_STEPS; t++) {
      const int par = t & 1;
      float ge = 0.f;
#pragma unroll
      for (int k = 0; k < 32; k++) {
        const int m = (k + seg) & 31;
        const float4 x = xbufE[par][seg * 32 + m];
        ge += we[k].x * x.x + we[k].y * x.y + we[k].z * x.z + we[k].w * x.w;
      }
      if (lane < 8)  // px term added once (seg 0)
        ge += px[((size_t)t * 1024 + (e << 3) + 2 * w + (idx & 1)) * 4 + g];
      ge += __shfl_xor(ge, 8, 64);
      ge += __shfl_xor(ge, 16, 64);
      ge += __shfl_xor(ge, 32, 64);
      // in-wave gate gather + cell (lanes 0,1), publish immediately
      const float gi = __shfl(ge, jc, 64), gf = __shfl(ge, 2 + jc, 64);
      const float gg = __shfl(ge, 4 + jc, 64), go = __shfl(ge, 6 + jc, 64);
      if (lane < 2) {
        const float c = sigf(gf) * ec + sigf(gi) * tanhf(gg);
        ec = c;
        const float h = sigf(go) * tanhf(c);
        st_bypass4(&ehbuf[(size_t)t * 1024 + (e << 3) + 2 * w + lane], h);
      }
      int ok;
      const fv4 ev = poll_pipe(&ehbuf[(size_t)t * 1024 + tid * 4], &ok);
      if (!ok) sbad = 1;
      xbufE[par ^ 1][tid] = make_float4(ev.x, ev.y, ev.z, ev.w);
      __syncthreads();  // the single per-step barrier
      if (sbad) break;
    }
  } else {
    // =========================== decoder group ===============================
    const int d = b - ENC_BLK;
    const int r = (g << 10) + (d << 3) + 2 * w + (idx & 1);  // owned gate row
    float4 w1[32], wr[32];
#pragma unroll
    for (int k = 0; k < 32; k++) {
      const int m = (k + seg) & 31;
      w1[k] = *(const float4*)&Wihd[(size_t)r * 2048 + seg * 128 + m * 4];
      const float4 a = *(const float4*)&Wihd[(size_t)r * 2048 + 1024 + seg * 128 + m * 4];
      const float4 c = *(const float4*)&Whhd[(size_t)r * 1024 + seg * 128 + m * 4];
      wr[k] = make_float4(a.x + c.x, a.y + c.y, a.z + c.z, a.w + c.w);
    }
    const float bdreg = bihd[r] + bhhd[r];
    aw[tid] = 0.f; aw[tid + 256] = 0.f;
    if (tid == 0) sbad = 0;
    float dc = 0.f;  // cell state (lanes 0,1 of each wave)
    const float4 wo = *(const float4*)&Wout[tid * 4];
    const float boutv = bout[0];
    __syncthreads();

    bool failed = false;
    for (int t = 0; t < T_STEPS; t++) {
      const int par = t & 1;
      // --- pre-dh: attention row, softmax partials over stale aw ---
      const float4 wae = *(const float4*)&Wattn[(size_t)t * 2048 + tid * 4];
      const float4 wad = *(const float4*)&Wattn[(size_t)t * 2048 + 1024 + tid * 4];
      const float battn_t = battn[t];
      const float ex0 = expf(aw[tid]);      // aw in [0,1]: exp safe, no max
      const float ex1 = expf(aw[tid + 256]);
      float so = ((tid == t) ? 0.f : ex0) + ((tid + 256 == t) ? 0.f : ex1);
#pragma unroll
      for (int mk = 1; mk <= 32; mk <<= 1) so += __shfl_xor(so, mk, 64);
      if (lane == 0) red[par][w] = so;

      // --- poll eh(t) (encoder runs ahead) ---
      int ok1;
      const fv4 ev = poll_pipe(&ehbuf[(size_t)t * 1024 + tid * 4], &ok1);
      if (!ok1) sbad = 1;
      float epe = wae.x * ev.x + wae.y * ev.y + wae.z * ev.z + wae.w * ev.w;
#pragma unroll
      for (int mk = 1; mk <= 32; mk <<= 1) epe += __shfl_xor(epe, mk, 64);
      if (lane == 0) redE[par][w] = epe;
      xbufD[tid] = make_float4(ev.x, ev.y, ev.z, ev.w);
      __syncthreads();  // B1
      if (sbad) { failed = true; break; }

      // --- g1 = Wihd[:,:H] @ eh(t), kept in registers (wave-own rows) ---
      float g1 = 0.f;
#pragma unroll
      for (int k = 0; k < 32; k++) {
        const int m = (k + seg) & 31;
        const float4 x = xbufD[seg * 32 + m];
        g1 += w1[k].x * x.x + w1[k].y * x.y + w1[k].z * x.z + w1[k].w * x.w;
      }
      g1 += __shfl_xor(g1, 8, 64);
      g1 += __shfl_xor(g1, 16, 64);
      g1 += __shfl_xor(g1, 32, 64);

      // --- poll dh(t-1): the recurrence-critical handoff ---
      fv4 dv = {0.f, 0.f, 0.f, 0.f};
      float epd = 0.f;
      if (t > 0) {
        int ok2;
        dv = poll_pipe(&dhbuf[(size_t)(t - 1) * 1024 + tid * 4], &ok2);
        if (!ok2) sbad = 1;
        epd = wad.x * dv.x + wad.y * dv.y + wad.z * dv.z + wad.w * dv.w;
      }
#pragma unroll
      for (int mk = 1; mk <= 32; mk <<= 1) epd += __shfl_xor(epd, mk, 64);
      if (lane == 0) redE2[par][w] = epd;
      dbufD[tid] = make_float4(dv.x, dv.y, dv.z, dv.w);
      __syncthreads();  // B2
      if (sbad) { failed = true; break; }

      // --- g2 = (Wihd[:,H:]+Whhd) @ dh(t-1) ---
      float g2 = 0.f;
#pragma unroll
      for (int k = 0; k < 32; k++) {
        const int m = (k + seg) & 31;
        const float4 dd = dbufD[seg * 32 + m];
        g2 += wr[k].x * dd.x + wr[k].y * dd.y + wr[k].z * dd.z + wr[k].w * dd.w;
      }
      g2 += __shfl_xor(g2, 8, 64);
      g2 += __shfl_xor(g2, 16, 64);
      g2 += __shfl_xor(g2, 32, 64);

      // --- softmax finish (all lanes redundantly) ---
      const float e_t = redE[par][0] + redE[par][1] + redE[par][2] + redE[par][3] +
                        redE2[par][0] + redE2[par][1] + redE2[par][2] + redE2[par][3] +
                        battn_t;
      const float exden = expf(e_t);
      const float inv = 1.f / (red[par][0] + red[par][1] + red[par][2] + red[par][3] + exden);
      const float awt = exden * inv;

      // --- cell via in-wave shuffles, publish immediately ---
      const float v = awt * g1 + g2 + bdreg;
      const float gi = __shfl(v, jc, 64), gf = __shfl(v, 2 + jc, 64);
      const float gg = __shfl(v, 4 + jc, 64), go = __shfl(v, 6 + jc, 64);
      if (lane < 2) {
        const float c = sigf(gf) * dc + sigf(gi) * tanhf(gg);
        dc = c;
        const float h = sigf(go) * tanhf(c);
        st_bypass4(&dhbuf[(size_t)t * 1024 + (d << 3) + 2 * w + lane], h);
      }
      // --- aw state update (own slots only; no cross-thread reads) ---
      aw[tid] = ((tid == t) ? exden : ex0) * inv;
      aw[tid + 256] = ((tid + 256 == t) ? exden : ex1) * inv;
    }

    // --- epilogue: out[t] = W_out·dh(t) + b_out, 4 t-values per block ---
    if (!failed) {
#pragma unroll
      for (int i = 0; i < 4; i++) {
        const int t = d * 4 + i;
        int ok;
        const fv4 dv = poll_pipe(&dhbuf[(size_t)t * 1024 + tid * 4], &ok);
        if (!ok) break;
        float op = wo.x * dv.x + wo.y * dv.y + wo.z * dv.z + wo.w * dv.w;
#pragma unroll
        for (int mk = 1; mk <= 32; mk <<= 1) op += __shfl_xor(op, mk, 64);
        if (lane == 0) red2[w] = op;
        __syncthreads();
        if (tid == 0) out[t] = red2[0] + red2[1] + red2[2] + red2[3] + boutv;
        __syncthreads();
      }
    }
  }
}

// ---------------------------------- launch ------------------------------------
extern "C" void kernel_launch(void* const* d_in, const int* in_sizes, int n_in,
                              void* d_out, int out_size, void* d_ws, size_t ws_size,
                              hipStream_t stream) {
  const float* X     = (const float*)d_in[0];
  const float* Wihe  = (const float*)d_in[2];
  const float* Whhe  = (const float*)d_in[3];
  const float* bihe  = (const float*)d_in[4];
  const float* bhhe  = (const float*)d_in[5];
  const float* Wattn = (const float*)d_in[6];
  const float* battn = (const float*)d_in[7];
  const float* Wihd  = (const float*)d_in[8];
  const float* Whhd  = (const float*)d_in[9];
  const float* bihd  = (const float*)d_in[10];
  const float* bhhd  = (const float*)d_in[11];
  const float* Wo    = (const float*)d_in[12];
  const float* bo    = (const float*)d_in[13];
  float* out = (float*)d_out;

  float* ws    = (float*)d_ws;
  float* px    = ws;                                  // 512*1024*4 floats (8 MB)
  float* ehbuf = px + (size_t)T_STEPS * 1024 * 4;     // 512*1024 (2 MB)
  float* dhbuf = ehbuf + (size_t)T_STEPS * 1024;      // 512*1024 (2 MB)
  const size_t need = ((size_t)T_STEPS * 1024 * 6) * sizeof(float);
  if (ws_size < need) return;

  prep_gemm<<<dim3(64, 8), 256, 0, stream>>>(X, Wihe, bihe, bhhe, px);
  lstm_persist<<<NBLK, 256, 0, stream>>>(
      Whhe, Wattn, battn, Wihd, Whhd, bihd, bhhd, Wo, bo, px, ehbuf, dhbuf, out);
}

// Round 8
// 1998.559 us; speedup vs baseline: 1.4443x; 1.4443x over previous
//
#include <hip/hip_runtime.h>
#include <math.h>

// TransformersLSTM: T=512, I=512, H=1024, L=512, O=1.
// Split-grid persistent kernel: blocks 0..127 encoder, 128..255 decoder.
// Weights VGPR-resident. Tagless handoff on 0xAA-poisoned write-once buffers
// (consumers spin on data granules, dword != 0xAAAAAAAA).
// R8 = R5 structure (best: 2087us) + two changes:
//  (1) 512-thread blocks: each wave owns 4 gate-rows x 16 lanes -> per-thread
//      K-slice halves; critical-path g2 matvec ~2x faster.
//  (2) 2-deep pipelined dwordx4 poll (sliding vmcnt(1)): sampling ~RTT/2 at
//      only 2x message rate. (R7's 4x scalar loads + multi-wave staggered
//      publication are both reverted — they caused the 2.9ms regression.)

#define T_STEPS 512
#define ENC_BLK 128
#define NBLK    256
#define NTHR    512
#define POLL_LIMIT 30000u

typedef float fv4 __attribute__((ext_vector_type(4)));

__device__ __forceinline__ float sigf(float x) { return 1.0f / (1.0f + expf(-x)); }

// 4B cache-bypass store (write-through to LLC); issued by one wave, coalesced.
__device__ __forceinline__ void st_bypass4(float* p, float v) {
  asm volatile("global_store_dword %0, %1, off sc0 sc1"
               :: "v"(p), "v"(v) : "memory");
}

__device__ __forceinline__ bool valid4(fv4 v) {
  return __float_as_uint(v.x) != 0xAAAAAAAAu && __float_as_uint(v.y) != 0xAAAAAAAAu &&
         __float_as_uint(v.z) != 0xAAAAAAAAu && __float_as_uint(v.w) != 0xAAAAAAAAu;
}

// 2-deep pipelined poison-poll of one 16B granule: two dwordx4 samples of the
// same address in flight; sliding vmcnt(1) window halves the sampling period.
__device__ __forceinline__ fv4 poll2(const float* p, int* okp) {
  fv4 a, b;
  int ok = 1;
  asm volatile("global_load_dwordx4 %0, %1, off sc0 sc1" : "=v"(a) : "v"(p) : "memory");
  for (unsigned it = 0;; ++it) {
    asm volatile("global_load_dwordx4 %0, %1, off sc0 sc1" : "=v"(b) : "v"(p) : "memory");
    asm volatile("s_waitcnt vmcnt(1)" : "+v"(a) :: "memory");  // oldest (a) done
    if (valid4(a)) { asm volatile("s_waitcnt vmcnt(0)" ::: "memory"); break; }
    asm volatile("global_load_dwordx4 %0, %1, off sc0 sc1" : "=v"(a) : "v"(p) : "memory");
    asm volatile("s_waitcnt vmcnt(1)" : "+v"(b) :: "memory");  // oldest (b) done
    if (valid4(b)) { asm volatile("s_waitcnt vmcnt(0)" ::: "memory"); a = b; break; }
    if (it > POLL_LIMIT) { ok = 0; asm volatile("s_waitcnt vmcnt(0)" ::: "memory"); break; }
  }
  *okp = ok;
  return a;
}

// ------------- precompute PX = W_ih_e @ x_t + b_ih_e + b_hh_e -----------------
// px[(t*1024 + h)*4 + g] for gate row r = g*1024 + h.
__global__ __launch_bounds__(256) void prep_gemm(const float* __restrict__ X,
                                                 const float* __restrict__ Wih,
                                                 const float* __restrict__ bih,
                                                 const float* __restrict__ bhh,
                                                 float* __restrict__ px) {
  __shared__ float Ws[64][68];
  __shared__ float Xs[64][68];
  const int r0 = blockIdx.x * 64;
  const int t0 = blockIdx.y * 64;
  const int tid = threadIdx.x;
  const int tr = tid & 15;
  const int tc = tid >> 4;
  float acc[4][4] = {{0.f}};
  for (int k0 = 0; k0 < 512; k0 += 64) {
    __syncthreads();
    const int lr = tid >> 4;
    const int lc = (tid & 15) * 4;
#pragma unroll
    for (int rep = 0; rep < 4; rep++) {
      const int row = lr + rep * 16;
      const float4 wv = *(const float4*)&Wih[(size_t)(r0 + row) * 512 + k0 + lc];
      Ws[lc + 0][row] = wv.x; Ws[lc + 1][row] = wv.y;
      Ws[lc + 2][row] = wv.z; Ws[lc + 3][row] = wv.w;
      const float4 xv = *(const float4*)&X[(size_t)(t0 + row) * 512 + k0 + lc];
      Xs[row][lc + 0] = xv.x; Xs[row][lc + 1] = xv.y;
      Xs[row][lc + 2] = xv.z; Xs[row][lc + 3] = xv.w;
    }
    __syncthreads();
    for (int kk = 0; kk < 64; kk++) {
      float a[4], x[4];
#pragma unroll
      for (int i = 0; i < 4; i++) a[i] = Ws[kk][tr * 4 + i];
#pragma unroll
      for (int j = 0; j < 4; j++) x[j] = Xs[tc * 4 + j][kk];
#pragma unroll
      for (int i = 0; i < 4; i++)
#pragma unroll
        for (int j = 0; j < 4; j++) acc[i][j] += a[i] * x[j];
    }
  }
#pragma unroll
  for (int i = 0; i < 4; i++) {
    const int r = r0 + tr * 4 + i;
    const int g = r >> 10, h = r & 1023;
    const float bsum = bih[r] + bhh[r];
#pragma unroll
    for (int j = 0; j < 4; j++) {
      const int t = t0 + tc * 4 + j;
      px[((size_t)t * 1024 + h) * 4 + g] = acc[i][j] + bsum;
    }
  }
}

// ------------------------------ persistent kernel -----------------------------
// 512 threads: wave w (0..7) owns gate g=w>>1, h-rows j=(w&1)*4+ri (ri=lane&3);
// lane s16=lane>>2 covers K in [s16*64, s16*64+64) as 16 float4 (rot by s16).
__global__ __launch_bounds__(512, 1) void lstm_persist(
    const float* __restrict__ Whhe, const float* __restrict__ Wattn,
    const float* __restrict__ battn, const float* __restrict__ Wihd,
    const float* __restrict__ Whhd, const float* __restrict__ bihd,
    const float* __restrict__ bhhd, const float* __restrict__ Wout,
    const float* __restrict__ bout, const float* __restrict__ px,
    float* ehbuf, float* dhbuf, float* out) {
  __shared__ float4 xbuf[256];   // eh copy (both groups)
  __shared__ float4 dbuf[256];   // dh copy (decoder)
  __shared__ float  aw[512];     // softmax state (decoder)
  __shared__ float  GA[32];      // gate sums (enc ge / dec g1)
  __shared__ float  GB[32];      // dec g2
  __shared__ float  bd[32];      // decoder bias
  __shared__ float  redE[4];     // energy (eh part)
  __shared__ float  redE2[4];    // energy (dh part)
  __shared__ float  red[8];      // softmax sums (8 waves)
  __shared__ float  red2[4];     // out-dot reduce
  __shared__ int    sbad;

  const int b    = blockIdx.x;
  const int tid  = threadIdx.x;
  const int w    = tid >> 6;
  const int lane = tid & 63;
  const int ri   = lane & 3;    // row-in-wave
  const int s16  = lane >> 2;   // K-segment 0..15 (64 floats)
  const int g    = w >> 1;      // gate index
  const int j    = ((w & 1) << 2) + ri;  // h-row within block's 8

  if (b < ENC_BLK) {
    // =========================== encoder group ===============================
    const int e = b;
    const int r = (g << 10) + (e << 3) + j;  // owned gate row
    float4 we[16];
#pragma unroll
    for (int k = 0; k < 16; k++) {
      const int m = (k + s16) & 15;
      we[k] = *(const float4*)&Whhe[(size_t)r * 1024 + s16 * 64 + m * 4];
    }
    if (tid < 256) xbuf[tid] = make_float4(0.f, 0.f, 0.f, 0.f);
    if (tid == 0) sbad = 0;
    float ec = 0.f;  // cell state (tid<8)
    __syncthreads();

    for (int t = 0; t < T_STEPS; t++) {
      float ge = 0.f;
#pragma unroll
      for (int k = 0; k < 16; k++) {
        const int m = (k + s16) & 15;
        const float4 x = xbuf[s16 * 16 + m];
        ge += we[k].x * x.x + we[k].y * x.y + we[k].z * x.z + we[k].w * x.w;
      }
      if (s16 == 0) ge += px[((size_t)t * 1024 + (e << 3) + j) * 4 + g];
      ge += __shfl_xor(ge, 4, 64);
      ge += __shfl_xor(ge, 8, 64);
      ge += __shfl_xor(ge, 16, 64);
      ge += __shfl_xor(ge, 32, 64);
      if (lane < 4) GA[w * 4 + lane] = ge;  // GA[g*8+j]
      __syncthreads();  // S1
      if (tid < 8) {
        const float gi = GA[tid], gf = GA[8 + tid], gg = GA[16 + tid], go = GA[24 + tid];
        const float c = sigf(gf) * ec + sigf(gi) * tanhf(gg);
        ec = c;
        const float h = sigf(go) * tanhf(c);
        st_bypass4(&ehbuf[(size_t)t * 1024 + (e << 3) + tid], h);  // coalesced 32B
      }
      int ok = 1;
      if (tid < 256) {
        const fv4 ev = poll2(&ehbuf[(size_t)t * 1024 + tid * 4], &ok);
        xbuf[tid] = make_float4(ev.x, ev.y, ev.z, ev.w);
      }
      if (!ok) sbad = 1;
      __syncthreads();  // S2
      if (sbad) break;
    }
  } else {
    // =========================== decoder group ===============================
    const int d = b - ENC_BLK;
    const int r = (g << 10) + (d << 3) + j;  // owned gate row
    float4 w1[16], wr[16];
#pragma unroll
    for (int k = 0; k < 16; k++) {
      const int m = (k + s16) & 15;
      w1[k] = *(const float4*)&Wihd[(size_t)r * 2048 + s16 * 64 + m * 4];
      const float4 a = *(const float4*)&Wihd[(size_t)r * 2048 + 1024 + s16 * 64 + m * 4];
      const float4 c = *(const float4*)&Whhd[(size_t)r * 1024 + s16 * 64 + m * 4];
      wr[k] = make_float4(a.x + c.x, a.y + c.y, a.z + c.z, a.w + c.w);
    }
    if (tid < 32) {
      const int gg2 = tid >> 3, jj2 = tid & 7;
      bd[tid] = bihd[(gg2 << 10) + (d << 3) + jj2] + bhhd[(gg2 << 10) + (d << 3) + jj2];
    }
    aw[tid] = 0.f;
    if (tid < 256) {
      xbuf[tid] = make_float4(0.f, 0.f, 0.f, 0.f);
      dbuf[tid] = make_float4(0.f, 0.f, 0.f, 0.f);
    }
    if (tid == 0) sbad = 0;
    float dc = 0.f;  // cell state (tid<8)
    float4 wo = make_float4(0.f, 0.f, 0.f, 0.f);
    if (tid < 256) wo = *(const float4*)&Wout[tid * 4];
    const float boutv = bout[0];
    __syncthreads();

    bool failed = false;
    for (int t = 0; t < T_STEPS; t++) {
      // --- pre-dh: softmax partials over stale aw (1 slot/thread) ---
      const float battn_t = battn[t];
      const float ex0 = expf(aw[tid]);  // aw in [0,1]: exp safe, no max needed
      float so = (tid == t) ? 0.f : ex0;
#pragma unroll
      for (int mk = 1; mk <= 32; mk <<= 1) so += __shfl_xor(so, mk, 64);
      if (lane == 0) red[w] = so;

      // --- poll eh(t) (encoder runs ahead) + eh energy dot ---
      float4 wae = make_float4(0.f, 0.f, 0.f, 0.f);
      float4 wad = make_float4(0.f, 0.f, 0.f, 0.f);
      float epe = 0.f;
      int ok1 = 1;
      if (tid < 256) {
        wae = *(const float4*)&Wattn[(size_t)t * 2048 + tid * 4];
        wad = *(const float4*)&Wattn[(size_t)t * 2048 + 1024 + tid * 4];
        const fv4 ev = poll2(&ehbuf[(size_t)t * 1024 + tid * 4], &ok1);
        epe = wae.x * ev.x + wae.y * ev.y + wae.z * ev.z + wae.w * ev.w;
        xbuf[tid] = make_float4(ev.x, ev.y, ev.z, ev.w);
      }
      if (!ok1) sbad = 1;
#pragma unroll
      for (int mk = 1; mk <= 32; mk <<= 1) epe += __shfl_xor(epe, mk, 64);
      if (lane == 0 && w < 4) redE[w] = epe;
      __syncthreads();  // B1
      if (sbad) { failed = true; break; }

      // --- g1 = Wihd[:,:H] @ eh(t) (dh-independent) ---
      float g1 = 0.f;
#pragma unroll
      for (int k = 0; k < 16; k++) {
        const int m = (k + s16) & 15;
        const float4 x = xbuf[s16 * 16 + m];
        g1 += w1[k].x * x.x + w1[k].y * x.y + w1[k].z * x.z + w1[k].w * x.w;
      }
      g1 += __shfl_xor(g1, 4, 64);
      g1 += __shfl_xor(g1, 8, 64);
      g1 += __shfl_xor(g1, 16, 64);
      g1 += __shfl_xor(g1, 32, 64);
      if (lane < 4) GA[w * 4 + lane] = g1;

      // --- poll dh(t-1): the recurrence-critical handoff ---
      float epd = 0.f;
      int ok2 = 1;
      if (t > 0 && tid < 256) {
        const fv4 dv = poll2(&dhbuf[(size_t)(t - 1) * 1024 + tid * 4], &ok2);
        epd = wad.x * dv.x + wad.y * dv.y + wad.z * dv.z + wad.w * dv.w;
        dbuf[tid] = make_float4(dv.x, dv.y, dv.z, dv.w);
      }
      if (!ok2) sbad = 1;
#pragma unroll
      for (int mk = 1; mk <= 32; mk <<= 1) epd += __shfl_xor(epd, mk, 64);
      if (lane == 0 && w < 4) redE2[w] = epd;
      __syncthreads();  // B2
      if (sbad) { failed = true; break; }

      // --- g2 = (Wihd[:,H:]+Whhd) @ dh(t-1) ---
      float g2 = 0.f;
#pragma unroll
      for (int k = 0; k < 16; k++) {
        const int m = (k + s16) & 15;
        const float4 dd = dbuf[s16 * 16 + m];
        g2 += wr[k].x * dd.x + wr[k].y * dd.y + wr[k].z * dd.z + wr[k].w * dd.w;
      }
      g2 += __shfl_xor(g2, 4, 64);
      g2 += __shfl_xor(g2, 8, 64);
      g2 += __shfl_xor(g2, 16, 64);
      g2 += __shfl_xor(g2, 32, 64);
      if (lane < 4) GB[w * 4 + lane] = g2;

      // --- softmax finish (all threads redundantly) + aw update ---
      const float e_t = redE[0] + redE[1] + redE[2] + redE[3] +
                        redE2[0] + redE2[1] + redE2[2] + redE2[3] + battn_t;
      const float exden = expf(e_t);
      const float inv = 1.f / (red[0] + red[1] + red[2] + red[3] +
                               red[4] + red[5] + red[6] + red[7] + exden);
      const float awt = exden * inv;
      aw[tid] = ((tid == t) ? exden : ex0) * inv;
      __syncthreads();  // S3 (GA/GB ready)

      // --- decoder cell (tid<8) + coalesced publication ---
      if (tid < 8) {
        const float gi = awt * GA[tid]      + GB[tid]      + bd[tid];
        const float gf = awt * GA[8 + tid]  + GB[8 + tid]  + bd[8 + tid];
        const float gg = awt * GA[16 + tid] + GB[16 + tid] + bd[16 + tid];
        const float go = awt * GA[24 + tid] + GB[24 + tid] + bd[24 + tid];
        const float c = sigf(gf) * dc + sigf(gi) * tanhf(gg);
        dc = c;
        const float h = sigf(go) * tanhf(c);
        st_bypass4(&dhbuf[(size_t)t * 1024 + (d << 3) + tid], h);
      }
    }

    // --- epilogue: out[t] = W_out·dh(t) + b_out, 4 t-values per block ---
    if (!failed) {
#pragma unroll
      for (int i = 0; i < 4; i++) {
        const int t = d * 4 + i;
        float op = 0.f;
        int ok = 1;
        if (tid < 256) {
          const fv4 dv = poll2(&dhbuf[(size_t)t * 1024 + tid * 4], &ok);
          op = wo.x * dv.x + wo.y * dv.y + wo.z * dv.z + wo.w * dv.w;
        }
        if (!ok) break;
#pragma unroll
        for (int mk = 1; mk <= 32; mk <<= 1) op += __shfl_xor(op, mk, 64);
        if (lane == 0 && w < 4) red2[w] = op;
        __syncthreads();
        if (tid == 0) out[t] = red2[0] + red2[1] + red2[2] + red2[3] + boutv;
        __syncthreads();
      }
    }
  }
}

// ---------------------------------- launch ------------------------------------
extern "C" void kernel_launch(void* const* d_in, const int* in_sizes, int n_in,
                              void* d_out, int out_size, void* d_ws, size_t ws_size,
                              hipStream_t stream) {
  const float* X     = (const float*)d_in[0];
  const float* Wihe  = (const float*)d_in[2];
  const float* Whhe  = (const float*)d_in[3];
  const float* bihe  = (const float*)d_in[4];
  const float* bhhe  = (const float*)d_in[5];
  const float* Wattn = (const float*)d_in[6];
  const float* battn = (const float*)d_in[7];
  const float* Wihd  = (const float*)d_in[8];
  const float* Whhd  = (const float*)d_in[9];
  const float* bihd  = (const float*)d_in[10];
  const float* bhhd  = (const float*)d_in[11];
  const float* Wo    = (const float*)d_in[12];
  const float* bo    = (const float*)d_in[13];
  float* out = (float*)d_out;

  float* ws    = (float*)d_ws;
  float* px    = ws;                                  // 512*1024*4 floats (8 MB)
  float* ehbuf = px + (size_t)T_STEPS * 1024 * 4;     // 512*1024 (2 MB)
  float* dhbuf = ehbuf + (size_t)T_STEPS * 1024;      // 512*1024 (2 MB)
  const size_t need = ((size_t)T_STEPS * 1024 * 6) * sizeof(float);
  if (ws_size < need) return;

  prep_gemm<<<dim3(64, 8), 256, 0, stream>>>(X, Wihe, bihe, bhhe, px);
  lstm_persist<<<NBLK, NTHR, 0, stream>>>(
      Whhe, Wattn, battn, Wihd, Whhd, bihd, bhhd, Wo, bo, px, ehbuf, dhbuf, out);
}